// Round 4
// baseline (298.221 us; speedup 1.0000x reference)
//
#include <hip/hip_runtime.h>
#include <hip/hip_bf16.h>
#include <cstddef>

// OutputAttention: context = softmax_s(tanh(passage@W1 + hidden@W2)@Vw) . passage
// B=32, S=2048, D=512, U=512. All inputs fp32; outputs fp32.
// d_out = context[32*512] ++ attn[32*2048]. attn region doubles as score scratch.

#define NB 32
#define NS 2048
#define ND 512
#define NU 512

typedef __bf16 bf16_t;
typedef __bf16 bf16x8 __attribute__((ext_vector_type(8)));
typedef float floatx4 __attribute__((ext_vector_type(4)));

// Async global->LDS DMA, 16B/lane (lands at lds_base + lane*16).
__device__ __forceinline__ void dma16(const void* g, void* l) {
    __builtin_amdgcn_global_load_lds(
        (const __attribute__((address_space(1))) unsigned int*)g,
        (__attribute__((address_space(3))) unsigned int*)l, 16, 0, 0);
}

// Inline-asm LDS read, b128. Deliberately hidden from the compiler's memory
// model: the waitcnt pass would otherwise insert `s_waitcnt vmcnt(0)` before
// any ds_read that may-alias an in-flight global_load_lds (same `ring` array,
// runtime offsets), draining the whole distance-3 DMA pipeline every kc.
// Caller owns the lgkmcnt wait + sched_barrier before consuming the result.
__device__ __forceinline__ floatx4 lds_read_b128(const float* p) {
    unsigned a = (unsigned)(size_t)(const __attribute__((address_space(3))) float*)p;
    floatx4 v;
    asm volatile("ds_read_b128 %0, %1" : "=v"(v) : "v"(a));
    return v;
}

// ---------------------------------------------------------------------------
// K0 fused: blocks [0,128): W1 fp32->bf16 swizzle into MFMA-B fragment order,
//           one 1KB frag per wave (gather-read, coalesced 16B writes).
//           blocks [128,256): hproj[b][u] = sum_d hidden[b][d]*W2[d][u].
// B-frag layout: frag f=(kc,ng); lane L holds B[kc*32+q*8+jj][ng*16+c], jj=0..7,
// at W1p[f*512 + L*8] -> k-loop B loads are one coalesced dwordx4 per lane.
__global__ __launch_bounds__(256) void prep_kernel(
    const float* __restrict__ W1, bf16_t* __restrict__ W1p,
    const float* __restrict__ hidden, const float* __restrict__ W2,
    float* __restrict__ hproj) {
    if (blockIdx.x < 128) {
        int wave = threadIdx.x >> 6, lane = threadIdx.x & 63;
        int f = (blockIdx.x << 2) + wave;             // 0..511
        int kc = f >> 5, ng = f & 31;
        int q = lane >> 4, c = lane & 15;
        const float* src = W1 + (kc * 32 + q * 8) * 512 + ng * 16 + c;
        bf16x8 w;
#pragma unroll
        for (int jj = 0; jj < 8; ++jj) w[jj] = (bf16_t)src[jj * 512];
        ((bf16x8*)W1p)[(f << 6) + lane] = w;
    } else {
        __shared__ float h[ND];
        __shared__ float part[256];
        int bi = blockIdx.x - 128;                    // 0..127
        int b = bi >> 2, ug = bi & 3;
        int t = threadIdx.x;
        h[t] = hidden[b * ND + t];
        h[t + 256] = hidden[b * ND + t + 256];
        __syncthreads();
        int u = (ug << 7) + (t & 127);
        int d0 = (t >> 7) << 8;                       // 0 or 256
        float acc = 0.f;
#pragma unroll 8
        for (int d = d0; d < d0 + 256; ++d) acc = fmaf(h[d], W2[d * NU + u], acc);
        part[t] = acc;
        __syncthreads();
        if (t < 128) hproj[b * NU + u] = part[t] + part[t + 128];
    }
}

// ---------------------------------------------------------------------------
// K2: scores[m] += sum_{n in half} tanh((passage@W1)[m][n] + hproj[b][n]) * Vw[n]
// Round-3 post-mortem: ring-4 + counted vmcnt gained only 11% (80us, all
// pipes <25%). Theory: compiler-inserted `vmcnt(0)` before each kc's ds_reads
// (may-alias vs the in-flight global_load_lds into another ring slot) drains
// the whole pipeline every iteration, making the hand-placed vmcnt(8)
// decorative. Fix: LDS reads via inline-asm ds_read_b128 (invisible to the
// waitcnt pass), batched 8/kc, then `s_waitcnt lgkmcnt(0)` + sched_barrier(0)
// (rule #18) before the cvt+MFMA block. Pipeline: ring-4, DMA distance-3,
// raw s_barrier with `vmcnt(8)` (proof: DMA(kc+1) has 8..12 newer vm-ops at
// the wait under any bb/DMA interleave -> waiting to <=8 outstanding always
// covers it, never drains DMA(kc+2/3) or bb(kc+1)). Prologue uses vmcnt(4)
// (safe under either issue order of bb0 vs slice DMAs).
// 4 waves x (64 rows x 64 cols) = 64x256 per block, N split across 2 blocks
// (atomicAdd combine). Regs ~155 < 170 cap of __launch_bounds__(256,3).
__global__ __launch_bounds__(256, 3) void score_kernel(
    const float* __restrict__ passage, const bf16_t* __restrict__ W1p,
    const float* __restrict__ hproj, const float* __restrict__ Vw,
    const float* __restrict__ Vb, float* __restrict__ scores) {
    __shared__ float ring[4 * 64 * 32];           // 4 slices x 8KB
    __shared__ float red[4 * 64];
    const int tid = threadIdx.x;
    const int wave = tid >> 6, lane = tid & 63;
    const int q = lane >> 4, c = lane & 15;
    const int bid = blockIdx.x;
    // bids xg*16+{sub, 8+sub} share a row-group and differ by 8 -> same XCD.
    const int mblk = ((bid >> 4) << 3) + (bid & 7); // 0..1023
    const int nhalf = (bid >> 3) & 1;               // n offset 0 / 256
    const int m0 = mblk * 64;
    const int b = m0 >> 11;
    const int ng0 = (nhalf << 4) + (wave << 2);     // 4 n-tiles per wave
    const bf16x8* Wq = (const bf16x8*)W1p;

    // Staging: wave w owns chunks {2w, 2w+1} (8 rows x 32 k = 1KB each).
    // Lane l of chunk ch: r = ch*8 + (l>>3), slot = l&7, k-unit = (slot-r)&7.
    const int ch0 = wave * 2;
    const int r0 = ch0 * 8 + (lane >> 3);
    const int k0 = ((lane & 7) - r0) & 7;
    const int r1 = r0 + 8;
    const int k1 = ((lane & 7) - r1) & 7;
    const float* g0 = passage + (size_t)(m0 + r0) * ND + k0 * 4;
    const float* g1 = passage + (size_t)(m0 + r1) * ND + k1 * 4;

    // DMA slice -> ring slot (slice & 3). dma-vs-dma order is preserved by
    // the compiler (possible LDS aliasing), which the wait counts rely on.
#define DMA_SLICE(slice) do {                                         \
        char* _l = (char*)ring + ((slice) & 3) * 8192 + ch0 * 1024;   \
        dma16(g0 + (slice) * 32, _l);                                 \
        dma16(g1 + (slice) * 32, _l + 1024);                          \
    } while (0)

    // Prologue: slices 0..2 in flight, then bb(0); fence pins DMAs oldest.
    DMA_SLICE(0);
    DMA_SLICE(1);
    DMA_SLICE(2);
    asm volatile("" ::: "memory");
    bf16x8 bb[2][4];
#pragma unroll
    for (int j = 0; j < 4; ++j)
        bb[0][j] = Wq[((ng0 + j) << 6) + lane];
    // vmcnt(4): drains slice-0 DMA whether bb0 issued before or after it.
    asm volatile("s_waitcnt vmcnt(4)");
    __builtin_amdgcn_s_barrier();

    floatx4 acc[4][4];
#pragma unroll
    for (int i = 0; i < 4; ++i)
#pragma unroll
        for (int j = 0; j < 4; ++j) { floatx4 z = {0.f, 0.f, 0.f, 0.f}; acc[i][j] = z; }

#pragma unroll
    for (int kc = 0; kc < 16; ++kc) {
        // Prefetch next B-frags into the other reg buffer (4 vm ops).
        if (kc < 15) {
#pragma unroll
            for (int j = 0; j < 4; ++j)
                bb[(kc + 1) & 1][j] = Wq[((((kc + 1) << 5) + ng0 + j) << 6) + lane];
        }
        // Prefetch slice kc+3 (2 vm ops) into slot (kc+3)&3 = slot of slice
        // kc-1, whose asm reads completed before the previous barrier (the
        // lgkmcnt(0) inside iter kc-1 retired them).
        if (kc + 3 < 16) DMA_SLICE(kc + 3);

        // Batched asm ds_reads of slot kc&3 (no compiler-inserted vmcnt).
        const float* sl = ring + (kc & 3) * 2048;
        floatx4 lo[4], hi[4];
#pragma unroll
        for (int i = 0; i < 4; ++i) {
            int r = i * 16 + c;
            const float* rp = sl + r * 32;
            lo[i] = lds_read_b128(rp + (((q << 1) + r) & 7) * 4);
            hi[i] = lds_read_b128(rp + (((q << 1) + 1 + r) & 7) * 4);
        }
        asm volatile("s_waitcnt lgkmcnt(0)");
        __builtin_amdgcn_sched_barrier(0);   // rule #18: pin consumers below

#pragma unroll
        for (int i = 0; i < 4; ++i) {
            bf16x8 a;
            a[0] = (bf16_t)lo[i][0]; a[1] = (bf16_t)lo[i][1];
            a[2] = (bf16_t)lo[i][2]; a[3] = (bf16_t)lo[i][3];
            a[4] = (bf16_t)hi[i][0]; a[5] = (bf16_t)hi[i][1];
            a[6] = (bf16_t)hi[i][2]; a[7] = (bf16_t)hi[i][3];
#pragma unroll
            for (int j = 0; j < 4; ++j)
                acc[i][j] = __builtin_amdgcn_mfma_f32_16x16x32_bf16(a, bb[kc & 1][j], acc[i][j], 0, 0, 0);
        }
        if (kc < 15) {
            // Counted wait: DMA(kc+1) (issued 2 iters ago) has >=8 newer vm
            // ops under any intra-iter ordering -> vmcnt(8) covers it while
            // keeping DMA(kc+2), DMA(kc+3), bb(kc+1) in flight.
            asm volatile("s_waitcnt vmcnt(8)");
            __builtin_amdgcn_s_barrier();
        }
    }
#undef DMA_SLICE

    // Epilogue: tanh(x) = 1 - 2/(1+e^{2x}); C/D layout col=c, row=i*16+q*4+r.
    float sp[4][4];
#pragma unroll
    for (int i = 0; i < 4; ++i)
#pragma unroll
        for (int r = 0; r < 4; ++r) sp[i][r] = 0.f;
#pragma unroll
    for (int j = 0; j < 4; ++j) {
        int n = ((ng0 + j) << 4) + c;
        float hp = hproj[(b << 9) + n];
        float vw = Vw[n];
#pragma unroll
        for (int i = 0; i < 4; ++i)
#pragma unroll
            for (int r = 0; r < 4; ++r) {
                float x = acc[i][j][r] + hp;
                float e = __expf(2.0f * x);
                float t = 1.0f - 2.0f * __builtin_amdgcn_rcpf(e + 1.0f);
                sp[i][r] = fmaf(t, vw, sp[i][r]);
            }
    }
#pragma unroll
    for (int off = 1; off < 16; off <<= 1)
#pragma unroll
        for (int i = 0; i < 4; ++i)
#pragma unroll
            for (int r = 0; r < 4; ++r)
                sp[i][r] += __shfl_xor(sp[i][r], off, 64);

    if (c == 0) {
#pragma unroll
        for (int i = 0; i < 4; ++i)
#pragma unroll
            for (int r = 0; r < 4; ++r)
                red[(wave << 6) + i * 16 + q * 4 + r] = sp[i][r];
    }
    __syncthreads();
    if (tid < 64) {
        float s = red[tid] + red[64 + tid] + red[128 + tid] + red[192 + tid];
        if (nhalf == 0) s += Vb[0];
        atomicAdd(&scores[m0 + tid], s);
    }
}

// ---------------------------------------------------------------------------
// K3: masked softmax over S, in place on attn. 32 blocks x 1024 threads.
__global__ __launch_bounds__(1024) void softmax_kernel(
    const float* __restrict__ mask, float* __restrict__ attn) {
    __shared__ float smx[16], ssm[16];
    int b = blockIdx.x, tid = threadIdx.x;
    int wave = tid >> 6, lane = tid & 63;
    const int base = b * NS;
    float v0 = attn[base + tid] + (1.0f - mask[base + tid]) * (-1e30f);
    float v1 = attn[base + 1024 + tid] + (1.0f - mask[base + 1024 + tid]) * (-1e30f);
    float mx = fmaxf(v0, v1);
#pragma unroll
    for (int off = 1; off < 64; off <<= 1) mx = fmaxf(mx, __shfl_xor(mx, off, 64));
    if (lane == 0) smx[wave] = mx;
    __syncthreads();
    mx = smx[0];
#pragma unroll
    for (int w = 1; w < 16; ++w) mx = fmaxf(mx, smx[w]);
    v0 = __expf(v0 - mx); v1 = __expf(v1 - mx);
    float sum = v0 + v1;
#pragma unroll
    for (int off = 1; off < 64; off <<= 1) sum += __shfl_xor(sum, off, 64);
    if (lane == 0) ssm[wave] = sum;
    __syncthreads();
    sum = 0.f;
#pragma unroll
    for (int w = 0; w < 16; ++w) sum += ssm[w];
    float inv = 1.0f / sum;
    attn[base + tid] = v0 * inv;
    attn[base + 1024 + tid] = v1 * inv;
}

// ---------------------------------------------------------------------------
// K4: context[b][d] = sum_s attn[b][s] * passage[b][s][d]. 1024 blocks x 512
// threads; 4 quarter-groups of 16 s-rows accumulate in regs, LDS-combine,
// one atomic per (block, d4).
__global__ __launch_bounds__(512) void context_kernel(
    const float* __restrict__ passage, const float* __restrict__ attn,
    float* __restrict__ ctx) {
    __shared__ float4 part[512];
    int bb = blockIdx.x >> 5, sc = blockIdx.x & 31, t = threadIdx.x;
    int col = t & 127, qh = t >> 7;
    const float4* p = (const float4*)(passage + (((size_t)bb * NS + sc * 64 + qh * 16) << 9));
    const float* wp = attn + bb * NS + sc * 64 + qh * 16;
    float ax = 0.f, ay = 0.f, az = 0.f, aw = 0.f;
#pragma unroll 16
    for (int s = 0; s < 16; ++s) {
        float w = wp[s];
        float4 v = p[(size_t)s * 128 + col];
        ax = fmaf(w, v.x, ax); ay = fmaf(w, v.y, ay);
        az = fmaf(w, v.z, az); aw = fmaf(w, v.w, aw);
    }
    float4 mine; mine.x = ax; mine.y = ay; mine.z = az; mine.w = aw;
    part[t] = mine;
    __syncthreads();
    if (t < 128) {
        float4 o1 = part[t + 128], o2 = part[t + 256], o3 = part[t + 384];
        float* dst = ctx + bb * ND + t * 4;
        atomicAdd(dst + 0, ax + o1.x + o2.x + o3.x);
        atomicAdd(dst + 1, ay + o1.y + o2.y + o3.y);
        atomicAdd(dst + 2, az + o1.z + o2.z + o3.z);
        atomicAdd(dst + 3, aw + o1.w + o2.w + o3.w);
    }
}

// ---------------------------------------------------------------------------
extern "C" void kernel_launch(void* const* d_in, const int* in_sizes, int n_in,
                              void* d_out, int out_size, void* d_ws, size_t ws_size,
                              hipStream_t stream) {
    const float* passage = (const float*)d_in[0];
    const float* hidden  = (const float*)d_in[1];
    const float* mask    = (const float*)d_in[2];
    const float* W1      = (const float*)d_in[3];
    const float* W2      = (const float*)d_in[4];
    const float* Vw      = (const float*)d_in[5];
    const float* Vb      = (const float*)d_in[6];

    float* ctx  = (float*)d_out;                    // [32*512]
    float* attn = (float*)d_out + NB * ND;          // [32*2048] (score scratch)

    bf16_t* W1p  = (bf16_t*)d_ws;                               // 512KB
    float* hproj = (float*)((char*)d_ws + (size_t)NU * ND * 2); // 64KB

    hipMemsetAsync(ctx, 0, (size_t)NB * (ND + NS) * sizeof(float), stream);
    prep_kernel<<<dim3(256), dim3(256), 0, stream>>>(W1, W1p, hidden, W2, hproj);
    score_kernel<<<dim3(2 * NB * NS / 64), dim3(256), 0, stream>>>(passage, W1p, hproj, Vw, Vb, attn);
    softmax_kernel<<<dim3(NB), dim3(1024), 0, stream>>>(mask, attn);
    context_kernel<<<dim3(NB * 32), dim3(512), 0, stream>>>(passage, attn, ctx);
}

// Round 5
// 269.952 us; speedup vs baseline: 1.1047x; 1.1047x over previous
//
#include <hip/hip_runtime.h>
#include <hip/hip_bf16.h>
#include <cstddef>

// OutputAttention: context = softmax_s(tanh(passage@W1 + hidden@W2)@Vw) . passage
// B=32, S=2048, D=512, U=512. All inputs fp32; outputs fp32.
// d_out = context[32*512] ++ attn[32*2048]. attn region doubles as score scratch.

#define NB 32
#define NS 2048
#define ND 512
#define NU 512

typedef __bf16 bf16_t;
typedef __bf16 bf16x8 __attribute__((ext_vector_type(8)));
typedef float floatx4 __attribute__((ext_vector_type(4)));

// Async global->LDS DMA, 16B/lane (lands at lds_base + lane*16).
__device__ __forceinline__ void dma16(const void* g, void* l) {
    __builtin_amdgcn_global_load_lds(
        (const __attribute__((address_space(1))) unsigned int*)g,
        (__attribute__((address_space(3))) unsigned int*)l, 16, 0, 0);
}

// Inline-asm LDS read, b128. Hidden from the compiler's memory model so the
// waitcnt pass cannot insert `s_waitcnt vmcnt(0)` before it (it would: the
// read may-alias the in-flight global_load_lds into another ring slot, and
// that conservative drain kills the distance-3 DMA pipeline every kc).
// Caller owns lgkmcnt waits + sched_barrier(0) before consuming results.
__device__ __forceinline__ floatx4 lds_read_b128(const float* p) {
    unsigned a = (unsigned)(size_t)(const __attribute__((address_space(3))) float*)p;
    floatx4 v;
    asm volatile("ds_read_b128 %0, %1" : "=v"(v) : "v"(a));
    return v;
}

// ---------------------------------------------------------------------------
// K0 fused: blocks [0,128): W1 fp32->bf16 swizzle into MFMA-B fragment order,
//           one 1KB frag per wave (gather-read, coalesced 16B writes).
//           blocks [128,256): hproj[b][u] = sum_d hidden[b][d]*W2[d][u].
// B-frag layout: frag f=(kc,ng); lane L holds B[kc*32+q*8+jj][ng*16+c], jj=0..7,
// at W1p[f*512 + L*8] -> k-loop B loads are one coalesced dwordx4 per lane.
__global__ __launch_bounds__(256) void prep_kernel(
    const float* __restrict__ W1, bf16_t* __restrict__ W1p,
    const float* __restrict__ hidden, const float* __restrict__ W2,
    float* __restrict__ hproj) {
    if (blockIdx.x < 128) {
        int wave = threadIdx.x >> 6, lane = threadIdx.x & 63;
        int f = (blockIdx.x << 2) + wave;             // 0..511
        int kc = f >> 5, ng = f & 31;
        int q = lane >> 4, c = lane & 15;
        const float* src = W1 + (kc * 32 + q * 8) * 512 + ng * 16 + c;
        bf16x8 w;
#pragma unroll
        for (int jj = 0; jj < 8; ++jj) w[jj] = (bf16_t)src[jj * 512];
        ((bf16x8*)W1p)[(f << 6) + lane] = w;
    } else {
        __shared__ float h[ND];
        __shared__ float part[256];
        int bi = blockIdx.x - 128;                    // 0..127
        int b = bi >> 2, ug = bi & 3;
        int t = threadIdx.x;
        h[t] = hidden[b * ND + t];
        h[t + 256] = hidden[b * ND + t + 256];
        __syncthreads();
        int u = (ug << 7) + (t & 127);
        int d0 = (t >> 7) << 8;                       // 0 or 256
        float acc = 0.f;
#pragma unroll 8
        for (int d = d0; d < d0 + 256; ++d) acc = fmaf(h[d], W2[d * NU + u], acc);
        part[t] = acc;
        __syncthreads();
        if (t < 128) hproj[b * NU + u] = part[t] + part[t + 128];
    }
}

// ---------------------------------------------------------------------------
// K2: scores[m] += sum_{n in half} tanh((passage@W1)[m][n] + hproj[b][n]) * Vw[n]
// Round-4 post-mortem: batching 8 asm ds_reads (lo[4]/hi[4], 32 VGPR live
// across the sched_barrier) + acc(64) + bb(32) blew the 170-reg cap ->
// scratch spill (WRITE_SIZE 53.7MB), confounding the alias-theory test.
// Round-5: same ring-4 / DMA-distance-3 / vmcnt(8) structure as round 3, but
// asm ds_reads in a chained 2-pair pipeline: issue p0,p1 -> lgkmcnt(2) ->
// cvt+MFMA(0) || issue p2 -> lgkmcnt(2) -> ... -> lgkmcnt(0) -> MFMA(3).
// Peak A-live = 16 regs; each wait followed by sched_barrier(0) (rule #18).
// The compiler never sees an LDS read aliasing the DMA -> no conservative
// vmcnt(0) per kc; the hand-placed vmcnt(8) finally governs the pipeline.
// vmcnt(8) proof (4 bb + 2 DMA vm-ops per iter): DMA(kc+1) was issued at
// iter kc-2; ops newer at the end-of-iter-kc wait: >=10 (kc<=13), 8 (kc=14)
// -> waiting to <=8 outstanding always retires DMA(kc+1), never drains
// DMA(kc+2), DMA(kc+3), bb(kc+1).
// 4 waves x (64 rows x 64 cols) = 64x256 per block, N split across 2 blocks
// (atomicAdd combine). Regs ~150 < 170 cap of __launch_bounds__(256,3).
__global__ __launch_bounds__(256, 3) void score_kernel(
    const float* __restrict__ passage, const bf16_t* __restrict__ W1p,
    const float* __restrict__ hproj, const float* __restrict__ Vw,
    const float* __restrict__ Vb, float* __restrict__ scores) {
    __shared__ float ring[4 * 64 * 32];           // 4 slices x 8KB
    __shared__ float red[4 * 64];
    const int tid = threadIdx.x;
    const int wave = tid >> 6, lane = tid & 63;
    const int q = lane >> 4, c = lane & 15;
    const int bid = blockIdx.x;
    // bids xg*16+{sub, 8+sub} share a row-group and differ by 8 -> same XCD.
    const int mblk = ((bid >> 4) << 3) + (bid & 7); // 0..1023
    const int nhalf = (bid >> 3) & 1;               // n offset 0 / 256
    const int m0 = mblk * 64;
    const int b = m0 >> 11;
    const int ng0 = (nhalf << 4) + (wave << 2);     // 4 n-tiles per wave
    const bf16x8* Wq = (const bf16x8*)W1p;

    // Staging: wave w owns chunks {2w, 2w+1} (8 rows x 32 k = 1KB each).
    // Lane l of chunk ch: r = ch*8 + (l>>3), slot = l&7, k-unit = (slot-r)&7.
    const int ch0 = wave * 2;
    const int r0 = ch0 * 8 + (lane >> 3);
    const int k0 = ((lane & 7) - r0) & 7;
    const int r1 = r0 + 8;
    const int k1 = ((lane & 7) - r1) & 7;
    const float* g0 = passage + (size_t)(m0 + r0) * ND + k0 * 4;
    const float* g1 = passage + (size_t)(m0 + r1) * ND + k1 * 4;

    // DMA slice -> ring slot (slice & 3). dma-vs-dma order is preserved by
    // the compiler (possible LDS aliasing), which the wait counts rely on.
#define DMA_SLICE(slice) do {                                         \
        char* _l = (char*)ring + ((slice) & 3) * 8192 + ch0 * 1024;   \
        dma16(g0 + (slice) * 32, _l);                                 \
        dma16(g1 + (slice) * 32, _l + 1024);                          \
    } while (0)

    // Prologue: slices 0..2 in flight, then bb(0); fence pins DMAs oldest.
    DMA_SLICE(0);
    DMA_SLICE(1);
    DMA_SLICE(2);
    asm volatile("" ::: "memory");
    bf16x8 bb[2][4];
#pragma unroll
    for (int j = 0; j < 4; ++j)
        bb[0][j] = Wq[((ng0 + j) << 6) + lane];
    // vmcnt(4): drains slice-0 DMA whether bb0 issued before or after it.
    asm volatile("s_waitcnt vmcnt(4)");
    __builtin_amdgcn_s_barrier();

    floatx4 acc[4][4];
#pragma unroll
    for (int i = 0; i < 4; ++i)
#pragma unroll
        for (int j = 0; j < 4; ++j) { floatx4 z = {0.f, 0.f, 0.f, 0.f}; acc[i][j] = z; }

    // Chained-read helpers. READ_PAIR issues 2 asm ds_reads for row-tile i;
    // CVT_MFMA consumes one pair into 4 MFMAs.
#define READ_PAIR(i, LO, HI) do {                                     \
        int r_ = (i) * 16 + c;                                        \
        const float* rp_ = sl + r_ * 32;                              \
        LO = lds_read_b128(rp_ + (((q << 1) + r_) & 7) * 4);          \
        HI = lds_read_b128(rp_ + (((q << 1) + 1 + r_) & 7) * 4);      \
    } while (0)
#define CVT_MFMA(i, LO, HI) do {                                      \
        bf16x8 a_;                                                    \
        a_[0] = (bf16_t)LO[0]; a_[1] = (bf16_t)LO[1];                 \
        a_[2] = (bf16_t)LO[2]; a_[3] = (bf16_t)LO[3];                 \
        a_[4] = (bf16_t)HI[0]; a_[5] = (bf16_t)HI[1];                 \
        a_[6] = (bf16_t)HI[2]; a_[7] = (bf16_t)HI[3];                 \
        _Pragma("unroll")                                             \
        for (int j_ = 0; j_ < 4; ++j_)                                \
            acc[i][j_] = __builtin_amdgcn_mfma_f32_16x16x32_bf16(     \
                a_, bb[kc & 1][j_], acc[i][j_], 0, 0, 0);             \
    } while (0)

#pragma unroll
    for (int kc = 0; kc < 16; ++kc) {
        // Prefetch next B-frags into the other reg buffer (4 vm ops).
        if (kc < 15) {
#pragma unroll
            for (int j = 0; j < 4; ++j)
                bb[(kc + 1) & 1][j] = Wq[((((kc + 1) << 5) + ng0 + j) << 6) + lane];
        }
        // Prefetch slice kc+3 (2 vm ops) into slot (kc+3)&3 = slot of slice
        // kc-1, whose asm reads retired inside iter kc-1 (lgkmcnt waits).
        if (kc + 3 < 16) DMA_SLICE(kc + 3);

        const float* sl = ring + (kc & 3) * 2048;
        floatx4 loA, hiA, loB, hiB, loC, hiC, loD, hiD;
        READ_PAIR(0, loA, hiA);
        READ_PAIR(1, loB, hiB);
        asm volatile("s_waitcnt lgkmcnt(2)");      // pair0 done, pair1 flies
        __builtin_amdgcn_sched_barrier(0);
        CVT_MFMA(0, loA, hiA);
        READ_PAIR(2, loC, hiC);
        asm volatile("s_waitcnt lgkmcnt(2)");      // pair1 done, pair2 flies
        __builtin_amdgcn_sched_barrier(0);
        CVT_MFMA(1, loB, hiB);
        READ_PAIR(3, loD, hiD);
        asm volatile("s_waitcnt lgkmcnt(2)");      // pair2 done, pair3 flies
        __builtin_amdgcn_sched_barrier(0);
        CVT_MFMA(2, loC, hiC);
        asm volatile("s_waitcnt lgkmcnt(0)");      // pair3 done
        __builtin_amdgcn_sched_barrier(0);
        CVT_MFMA(3, loD, hiD);

        if (kc < 15) {
            // Counted wait: retires DMA(kc+1) (issued 2 iters ago) while
            // keeping DMA(kc+2), DMA(kc+3), bb(kc+1) in flight.
            asm volatile("s_waitcnt vmcnt(8)");
            __builtin_amdgcn_s_barrier();
        }
    }
#undef CVT_MFMA
#undef READ_PAIR
#undef DMA_SLICE

    // Epilogue: tanh(x) = 1 - 2/(1+e^{2x}); C/D layout col=c, row=i*16+q*4+r.
    float sp[4][4];
#pragma unroll
    for (int i = 0; i < 4; ++i)
#pragma unroll
        for (int r = 0; r < 4; ++r) sp[i][r] = 0.f;
#pragma unroll
    for (int j = 0; j < 4; ++j) {
        int n = ((ng0 + j) << 4) + c;
        float hp = hproj[(b << 9) + n];
        float vw = Vw[n];
#pragma unroll
        for (int i = 0; i < 4; ++i)
#pragma unroll
            for (int r = 0; r < 4; ++r) {
                float x = acc[i][j][r] + hp;
                float e = __expf(2.0f * x);
                float t = 1.0f - 2.0f * __builtin_amdgcn_rcpf(e + 1.0f);
                sp[i][r] = fmaf(t, vw, sp[i][r]);
            }
    }
#pragma unroll
    for (int off = 1; off < 16; off <<= 1)
#pragma unroll
        for (int i = 0; i < 4; ++i)
#pragma unroll
            for (int r = 0; r < 4; ++r)
                sp[i][r] += __shfl_xor(sp[i][r], off, 64);

    if (c == 0) {
#pragma unroll
        for (int i = 0; i < 4; ++i)
#pragma unroll
            for (int r = 0; r < 4; ++r)
                red[(wave << 6) + i * 16 + q * 4 + r] = sp[i][r];
    }
    __syncthreads();
    if (tid < 64) {
        float s = red[tid] + red[64 + tid] + red[128 + tid] + red[192 + tid];
        if (nhalf == 0) s += Vb[0];
        atomicAdd(&scores[m0 + tid], s);
    }
}

// ---------------------------------------------------------------------------
// K3: masked softmax over S, in place on attn. 32 blocks x 1024 threads.
__global__ __launch_bounds__(1024) void softmax_kernel(
    const float* __restrict__ mask, float* __restrict__ attn) {
    __shared__ float smx[16], ssm[16];
    int b = blockIdx.x, tid = threadIdx.x;
    int wave = tid >> 6, lane = tid & 63;
    const int base = b * NS;
    float v0 = attn[base + tid] + (1.0f - mask[base + tid]) * (-1e30f);
    float v1 = attn[base + 1024 + tid] + (1.0f - mask[base + 1024 + tid]) * (-1e30f);
    float mx = fmaxf(v0, v1);
#pragma unroll
    for (int off = 1; off < 64; off <<= 1) mx = fmaxf(mx, __shfl_xor(mx, off, 64));
    if (lane == 0) smx[wave] = mx;
    __syncthreads();
    mx = smx[0];
#pragma unroll
    for (int w = 1; w < 16; ++w) mx = fmaxf(mx, smx[w]);
    v0 = __expf(v0 - mx); v1 = __expf(v1 - mx);
    float sum = v0 + v1;
#pragma unroll
    for (int off = 1; off < 64; off <<= 1) sum += __shfl_xor(sum, off, 64);
    if (lane == 0) ssm[wave] = sum;
    __syncthreads();
    sum = 0.f;
#pragma unroll
    for (int w = 0; w < 16; ++w) sum += ssm[w];
    float inv = 1.0f / sum;
    attn[base + tid] = v0 * inv;
    attn[base + 1024 + tid] = v1 * inv;
}

// ---------------------------------------------------------------------------
// K4: context[b][d] = sum_s attn[b][s] * passage[b][s][d]. 1024 blocks x 512
// threads; 4 quarter-groups of 16 s-rows accumulate in regs, LDS-combine,
// one atomic per (block, d4).
__global__ __launch_bounds__(512) void context_kernel(
    const float* __restrict__ passage, const float* __restrict__ attn,
    float* __restrict__ ctx) {
    __shared__ float4 part[512];
    int bb = blockIdx.x >> 5, sc = blockIdx.x & 31, t = threadIdx.x;
    int col = t & 127, qh = t >> 7;
    const float4* p = (const float4*)(passage + (((size_t)bb * NS + sc * 64 + qh * 16) << 9));
    const float* wp = attn + bb * NS + sc * 64 + qh * 16;
    float ax = 0.f, ay = 0.f, az = 0.f, aw = 0.f;
#pragma unroll 16
    for (int s = 0; s < 16; ++s) {
        float w = wp[s];
        float4 v = p[(size_t)s * 128 + col];
        ax = fmaf(w, v.x, ax); ay = fmaf(w, v.y, ay);
        az = fmaf(w, v.z, az); aw = fmaf(w, v.w, aw);
    }
    float4 mine; mine.x = ax; mine.y = ay; mine.z = az; mine.w = aw;
    part[t] = mine;
    __syncthreads();
    if (t < 128) {
        float4 o1 = part[t + 128], o2 = part[t + 256], o3 = part[t + 384];
        float* dst = ctx + bb * ND + t * 4;
        atomicAdd(dst + 0, ax + o1.x + o2.x + o3.x);
        atomicAdd(dst + 1, ay + o1.y + o2.y + o3.y);
        atomicAdd(dst + 2, az + o1.z + o2.z + o3.z);
        atomicAdd(dst + 3, aw + o1.w + o2.w + o3.w);
    }
}

// ---------------------------------------------------------------------------
extern "C" void kernel_launch(void* const* d_in, const int* in_sizes, int n_in,
                              void* d_out, int out_size, void* d_ws, size_t ws_size,
                              hipStream_t stream) {
    const float* passage = (const float*)d_in[0];
    const float* hidden  = (const float*)d_in[1];
    const float* mask    = (const float*)d_in[2];
    const float* W1      = (const float*)d_in[3];
    const float* W2      = (const float*)d_in[4];
    const float* Vw      = (const float*)d_in[5];
    const float* Vb      = (const float*)d_in[6];

    float* ctx  = (float*)d_out;                    // [32*512]
    float* attn = (float*)d_out + NB * ND;          // [32*2048] (score scratch)

    bf16_t* W1p  = (bf16_t*)d_ws;                               // 512KB
    float* hproj = (float*)((char*)d_ws + (size_t)NU * ND * 2); // 64KB

    hipMemsetAsync(ctx, 0, (size_t)NB * (ND + NS) * sizeof(float), stream);
    prep_kernel<<<dim3(256), dim3(256), 0, stream>>>(W1, W1p, hidden, W2, hproj);
    score_kernel<<<dim3(2 * NB * NS / 64), dim3(256), 0, stream>>>(passage, W1p, hproj, Vw, Vb, attn);
    softmax_kernel<<<dim3(NB), dim3(1024), 0, stream>>>(mask, attn);
    context_kernel<<<dim3(NB * 32), dim3(512), 0, stream>>>(passage, attn, ctx);
}